// Round 10
// baseline (91.696 us; speedup 1.0000x reference)
//
#include <hip/hip_runtime.h>

// LDS forward collapsed to causal conv:
//   y[b,t,o] = sum_{d<=t} x[b,t-d] * K[d,o] + G[t,o]
//   K[d,o] = sum_s C[s,o] A[s]^d B[s]  (+ M[o,0,d-1] for d in 1..5)
//   G[t,o] = sum_s C[s,o] A[s]^{t+1} h0[s]
//
// R10: k_main blocks = 512t x 32o (16 o-chunks x 16 batch-groups = 256 = 1/CU),
// 8 waves each owning 64t x 32o (mi=0..3, ni=0..1) -> every 128B output line
// is written whole by ONE wave (2 back-to-back float4 stores). B-frags in regs
// (128 VGPR), Toeplitz A-frags from LDS w/ diagonal reuse (6-slot window).
// Staging via global_load_lds double-buffer; batch barrier = counted vmcnt(8)
// so current stores drain across the boundary. prep: unroll-8 C pipeline.

typedef __attribute__((ext_vector_type(8))) short short8v;
typedef __attribute__((ext_vector_type(4))) float float4v;

#define NB 16
#define SIG(e) ((e) + ((e) >> 3))           // pad: entry e -> slot e + e/8
#define AWI(j) ((((j) % 6) + 6) % 6)        // rolling window slot (compile-time)

static __device__ __forceinline__ unsigned short f2bf(float f) {
    union { float f; unsigned int u; } x; x.f = f;
    unsigned int r = x.u + 0x7fffu + ((x.u >> 16) & 1u);  // RNE
    return (unsigned short)(r >> 16);
}

// ---------------- prep: KT/G (blocks 0..1023) + XS (blocks 1024..1279) ----
__global__ __launch_bounds__(256) void k_prep(const float* __restrict__ A,
                                              const float* __restrict__ B,
                                              const float* __restrict__ h0,
                                              const float* __restrict__ C,
                                              const float* __restrict__ M,
                                              const float* __restrict__ x,
                                              unsigned short* __restrict__ KT,
                                              float* __restrict__ G,
                                              short8v* __restrict__ XS) {
    __shared__ float PBL[512][4];
    __shared__ float PHL[512][4];
    __shared__ float red[4][64][8];
    __shared__ unsigned short xs[512];
    const int tid = threadIdx.x;

    if (blockIdx.x < 1024) {
        // ---- ktg unit: 64 o x 4 d ----
        const int d0 = (blockIdx.x & 127) * 4;
        const int oc = blockIdx.x >> 7;

        // phase A: power tables for this d-chunk (exact binpow, f32)
        #pragma unroll
        for (int q = 0; q < 2; ++q) {
            int ss = tid + q * 256;
            float a = A[ss];
            float r = 1.0f, base = a;
            #pragma unroll
            for (int bit = 0; bit < 9; ++bit) {       // d0 <= 508
                if (d0 & (1 << bit)) r *= base;
                base *= base;
            }
            float bs = B[ss], hs = h0[ss];
            #pragma unroll
            for (int j = 0; j < 4; ++j) {
                PBL[ss][j] = r * bs;          // A^(d0+j) * B
                PHL[ss][j] = r * a * hs;      // A^(d0+j+1) * h0
                r *= a;
            }
        }
        __syncthreads();

        // phase B: s-reduction, 4 waves x 128 s, 8-deep load pipeline
        const int lane = tid & 63;
        const int sc   = tid >> 6;
        const int o    = oc * 64 + lane;
        float kt[4] = {0.f, 0.f, 0.f, 0.f};
        float gg[4] = {0.f, 0.f, 0.f, 0.f};
        for (int si = 0; si < 128; si += 8) {
            float c8[8];
            #pragma unroll
            for (int u = 0; u < 8; ++u)
                c8[u] = C[(sc * 128 + si + u) * 512 + o];
            #pragma unroll
            for (int u = 0; u < 8; ++u) {
                int s = sc * 128 + si + u;
                #pragma unroll
                for (int j = 0; j < 4; ++j) {
                    kt[j] = fmaf(PBL[s][j], c8[u], kt[j]);
                    gg[j] = fmaf(PHL[s][j], c8[u], gg[j]);
                }
            }
        }
        #pragma unroll
        for (int j = 0; j < 4; ++j) {
            red[sc][lane][j]     = kt[j];
            red[sc][lane][j + 4] = gg[j];
        }
        __syncthreads();
        if (sc == 0) {
            #pragma unroll
            for (int j = 0; j < 4; ++j) {
                float v  = red[0][lane][j] + red[1][lane][j]
                         + red[2][lane][j] + red[3][lane][j];
                float gv = red[0][lane][j+4] + red[1][lane][j+4]
                         + red[2][lane][j+4] + red[3][lane][j+4];
                int d = d0 + j;
                if (d >= 1 && d <= 5) v += M[o * 5 + (d - 1)];   // AR taps
                KT[o * 512 + d] = f2bf(v);
                G[d * 512 + o]  = gv;
            }
        }
    } else {
        // ---- xprep unit: one batch ----
        const int b = blockIdx.x - 1024;
        #pragma unroll
        for (int q = 0; q < 2; ++q) {
            int i = tid * 2 + q;
            xs[i] = f2bf(x[b * 512 + 511 - i]);
        }
        __syncthreads();
        short8v* dst = XS + (size_t)b * 1216;
        for (int s2 = tid; s2 < 1216; s2 += 256) {
            if (s2 % 9 == 8 || s2 > 1150) dst[s2] = (short8v)(short)0;
        }
        #pragma unroll
        for (int q = 0; q < 4; ++q) {
            int e = tid * 4 + q;
            short8v v;
            #pragma unroll
            for (int jj = 0; jj < 8; ++jj) {
                int i = e + jj;
                v[jj] = (i < 512) ? (short)xs[i] : (short)0;
            }
            dst[SIG(e)] = v;
        }
    }
}

// ---------------- main: 256 blocks, 512 threads, block = 512t x 32o --------
__global__ __launch_bounds__(512, 2) void k_main(const short8v* __restrict__ XS,
                                                 const unsigned short* __restrict__ KT,
                                                 const float* __restrict__ G,
                                                 float* __restrict__ out) {
    __shared__ short8v xbuf[2][1216];     // 38 KB, sigma-padded octet tables

    const int bo0 = blockIdx.x * 32;
    const int b0  = blockIdx.y * NB;
    const int tid = threadIdx.x;
    const int lane = tid & 63;
    const int wv   = tid >> 6;          // 0..7  -> t-chunk
    const int t0w  = wv * 64;
    const int lrow = lane & 15;
    const int g    = lane >> 4;

    // ---- prologue: stage batch 0 via global_load_lds, B-regs, G-regs ----
    {
        const short8v* src = XS + (size_t)b0 * 1216;
        for (int c = wv; c < 19; c += 8)
            __builtin_amdgcn_global_load_lds(
                (const __attribute__((address_space(1))) void*)(src + c * 64 + lane),
                (__attribute__((address_space(3))) void*)(&xbuf[0][c * 64]),
                16, 0, 0);
    }

    short8v bfr[2][16];                   // full 32-o B slice of this block
    #pragma unroll
    for (int ni = 0; ni < 2; ++ni) {
        const unsigned short* bp = KT + (bo0 + ni * 16 + lrow) * 512 + g * 8;
        #pragma unroll
        for (int ks = 0; ks < 16; ++ks)
            bfr[ni][ks] = *(const short8v*)(bp + ks * 32);
    }

    float4v gacc[4][2];                   // batch-invariant G tile
    #pragma unroll
    for (int mi = 0; mi < 4; ++mi)
        #pragma unroll
        for (int ni = 0; ni < 2; ++ni)
            gacc[mi][ni] = *(const float4v*)(G + (t0w + mi * 16 + lrow) * 512
                                               + bo0 + ni * 16 + g * 4);

    asm volatile("s_waitcnt vmcnt(0)" ::: "memory");
    __builtin_amdgcn_s_barrier();

    const int E0 = 511 - t0w - lrow + g * 8;   // frag j at SIG(E0 + 16*j)

    int p = 0;
    for (int bi = 0; bi < NB; ++bi) {
        const int b = b0 + bi;

        // issue next batch's staging (drains under the MFMA loop)
        if (bi + 1 < NB) {
            const short8v* src = XS + (size_t)(b + 1) * 1216;
            short8v* dstb = xbuf[p ^ 1];
            for (int c = wv; c < 19; c += 8)
                __builtin_amdgcn_global_load_lds(
                    (const __attribute__((address_space(1))) void*)(src + c * 64 + lane),
                    (__attribute__((address_space(3))) void*)(dstb + c * 64),
                    16, 0, 0);
        }

        const short8v* xo = xbuf[p];

        float4v acc[4][2];
        #pragma unroll
        for (int mi = 0; mi < 4; ++mi)
            #pragma unroll
            for (int ni = 0; ni < 2; ++ni)
                acc[mi][ni] = (float4v)(0.0f);

        // A window: frags j = 2ks-3 .. 2ks live, 2 refills per k-step
        short8v aw[6];
        #pragma unroll
        for (int j = -3; j <= 0; ++j)
            aw[AWI(j)] = xo[SIG(E0 + 16 * j)];

        #pragma unroll
        for (int ks = 0; ks < 16; ++ks) {
            acc[3][0] = __builtin_amdgcn_mfma_f32_16x16x32_bf16(
                bfr[0][ks], aw[AWI(2 * ks - 3)], acc[3][0], 0, 0, 0);
            acc[3][1] = __builtin_amdgcn_mfma_f32_16x16x32_bf16(
                bfr[1][ks], aw[AWI(2 * ks - 3)], acc[3][1], 0, 0, 0);
            acc[2][0] = __builtin_amdgcn_mfma_f32_16x16x32_bf16(
                bfr[0][ks], aw[AWI(2 * ks - 2)], acc[2][0], 0, 0, 0);
            acc[2][1] = __builtin_amdgcn_mfma_f32_16x16x32_bf16(
                bfr[1][ks], aw[AWI(2 * ks - 2)], acc[2][1], 0, 0, 0);
            if (ks < 15) {
                aw[AWI(2 * ks + 1)] = xo[SIG(E0 + 16 * (2 * ks + 1))];
                aw[AWI(2 * ks + 2)] = xo[SIG(E0 + 16 * (2 * ks + 2))];
            }
            acc[1][0] = __builtin_amdgcn_mfma_f32_16x16x32_bf16(
                bfr[0][ks], aw[AWI(2 * ks - 1)], acc[1][0], 0, 0, 0);
            acc[1][1] = __builtin_amdgcn_mfma_f32_16x16x32_bf16(
                bfr[1][ks], aw[AWI(2 * ks - 1)], acc[1][1], 0, 0, 0);
            acc[0][0] = __builtin_amdgcn_mfma_f32_16x16x32_bf16(
                bfr[0][ks], aw[AWI(2 * ks)], acc[0][0], 0, 0, 0);
            acc[0][1] = __builtin_amdgcn_mfma_f32_16x16x32_bf16(
                bfr[1][ks], aw[AWI(2 * ks)], acc[0][1], 0, 0, 0);
        }

        // epilogue: per t, THIS wave writes the full 128B line (ni=0 then 1)
        float* op = out + (size_t)b * 262144;
        #pragma unroll
        for (int mi = 0; mi < 4; ++mi) {
            const int t = t0w + mi * 16 + lrow;
            float* rp = op + t * 512 + bo0 + g * 4;
            *(float4v*)(rp)      = acc[mi][0] + gacc[mi][0];
            *(float4v*)(rp + 16) = acc[mi][1] + gacc[mi][1];
        }

        // counted-vmcnt barrier: forces stage (+older stores) retired, lets
        // the 8 newest stores (this batch) drain across the boundary.
        if (bi + 1 < NB) {
            asm volatile("s_waitcnt vmcnt(8)" ::: "memory");
            __builtin_amdgcn_s_barrier();
            p ^= 1;
        }
    }
}

extern "C" void kernel_launch(void* const* d_in, const int* in_sizes, int n_in,
                              void* d_out, int out_size, void* d_ws, size_t ws_size,
                              hipStream_t stream) {
    const float* x  = (const float*)d_in[0];   // [256,512,1]
    const float* A  = (const float*)d_in[1];   // [512]
    const float* B  = (const float*)d_in[2];   // [1,512]
    const float* C  = (const float*)d_in[3];   // [512,512]
    const float* M  = (const float*)d_in[4];   // [512,1,5]
    const float* h0 = (const float*)d_in[5];   // [512]
    float* out = (float*)d_out;

    char* ws = (char*)d_ws;
    unsigned short* KT = (unsigned short*)ws;                  // 512 KB
    float*          G  = (float*)(ws + (1u << 19));            // 1 MB
    short8v*        XS = (short8v*)(ws + (1u << 19) + (1u << 20)); // ~4.75 MB

    k_prep<<<1280, 256, 0, stream>>>(A, B, h0, C, M, x, KT, G, XS);
    k_main<<<dim3(16, 16), 512, 0, stream>>>(XS, KT, G, out);
}